// Round 9
// baseline (99.667 us; speedup 1.0000x reference)
//
#include <hip/hip_runtime.h>

typedef __bf16 bf16x8 __attribute__((ext_vector_type(8)));
typedef __bf16 bf16x4 __attribute__((ext_vector_type(4)));
typedef float f32x4 __attribute__((ext_vector_type(4)));
typedef float f32x16 __attribute__((ext_vector_type(16)));
typedef unsigned int u32;

#define T_LEN 4096

__device__ __forceinline__ f32x4 mfma16(bf16x8 a, bf16x8 b, f32x4 c) {
    return __builtin_amdgcn_mfma_f32_16x16x32_bf16(a, b, c, 0, 0, 0);
}
__device__ __forceinline__ f32x16 mfma32(bf16x8 a, bf16x8 b, f32x16 c) {
    return __builtin_amdgcn_mfma_f32_32x32x16_bf16(a, b, c, 0, 0, 0);
}
__device__ __forceinline__ u32 packbf(float lo, float hi) {
    union { __bf16 e[2]; u32 w; } u;
    u.e[0] = (__bf16)lo; u.e[1] = (__bf16)hi;
    return u.w;
}
__device__ __forceinline__ f32x16 zero16() {
    f32x16 z;
    #pragma unroll
    for (int i = 0; i < 16; i++) z[i] = 0.f;
    return z;
}

// ---------------- W fp32 -> bf16 (ws), vectorized ----------------
__global__ __launch_bounds__(256) void convert_w_kernel(
    const float* __restrict__ Wq, const float* __restrict__ Wk,
    const float* __restrict__ Wv, __bf16* __restrict__ wb)
{
    int i = blockIdx.x * 256 + threadIdx.x;      // 49152 threads, 4 elems each
    int m = i >> 14, off = (i & 16383) << 2;
    const float* s = (m == 0 ? Wq : (m == 1 ? Wk : Wv)) + off;
    float4 f = *(const float4*)s;
    bf16x4 h = { (__bf16)f.x, (__bf16)f.y, (__bf16)f.z, (__bf16)f.w };
    *(bf16x4*)(wb + (m << 16) + off) = h;
}

// ------ QKV projection (M=16384,N=192,K=1024) + fused RoPE + q-prescale ------
// 1024 blocks x 16 rows, 4 waves (one 48-col N-group each). x staged via a tiny
// 4.6 KB LDS double-buffer (shared by the 4 waves); W B-frags read directly
// from L2 (wb is 384 KB, L2-resident; loads hoistable across barriers).
__global__ __launch_bounds__(256) void proj_kernel(
    const float* __restrict__ x, const __bf16* __restrict__ wb,
    __bf16* __restrict__ qb, __bf16* __restrict__ kb, __bf16* __restrict__ vt)
{
    __shared__ __bf16 xs[2][16][72];
    const int tid  = threadIdx.x;
    const int wave = tid >> 6, lane = tid & 63;
    const int l15 = lane & 15, l4 = lane >> 4;
    const size_t m0 = (size_t)blockIdx.x * 16;
    const int xrow = tid >> 4, xc4 = (tid & 15) * 4;   // x stage: 16 thr/row

    f32x4 acc[3];
    #pragma unroll
    for (int bn = 0; bn < 3; bn++) acc[bn] = (f32x4){0.f, 0.f, 0.f, 0.f};

    const float* xsrc = x + (m0 + xrow) * 1024 + xc4;
    const __bf16* wbase = wb + (size_t)(wave * 48 + l15) * 1024 + l4 * 8;

    float4 rx = *(const float4*)xsrc;
    {
        bf16x4 hx = {(__bf16)rx.x, (__bf16)rx.y, (__bf16)rx.z, (__bf16)rx.w};
        *(bf16x4*)&xs[0][xrow][xc4] = hx;
    }
    __syncthreads();

    for (int t = 0; t < 16; t++) {
        const int cur = t & 1;
        const int k0 = t * 64;
        if (t < 15) rx = *(const float4*)(xsrc + k0 + 64);
        bf16x8 af0 = *(const bf16x8*)&xs[cur][l15][l4 * 8];
        bf16x8 af1 = *(const bf16x8*)&xs[cur][l15][32 + l4 * 8];
        #pragma unroll
        for (int nf = 0; nf < 3; nf++) {
            bf16x8 b0 = *(const bf16x8*)(wbase + (size_t)nf * 16384 + k0);
            bf16x8 b1 = *(const bf16x8*)(wbase + (size_t)nf * 16384 + k0 + 32);
            acc[nf] = mfma16(af0, b0, acc[nf]);
            acc[nf] = mfma16(af1, b1, acc[nf]);
        }
        if (t < 15) {
            bf16x4 hx = {(__bf16)rx.x, (__bf16)rx.y, (__bf16)rx.z, (__bf16)rx.w};
            *(bf16x4*)&xs[cur ^ 1][xrow][xc4] = hx;
        }
        __syncthreads();
    }

    // epilogue: C layout col = l15 (n), row = l4*4 + r (m); rope fused for q,k;
    // q additionally pre-scaled by (1/8)*log2(e) so flash softmax is base-2 direct.
    #pragma unroll
    for (int nf = 0; nf < 3; nf++) {
        int n = wave * 48 + nf * 16 + l15;
        #pragma unroll
        for (int r = 0; r < 4; r++) {
            size_t mrow = m0 + l4 * 4 + r;
            float val = acc[nf][r];
            float partner = __shfl_xor(val, 1);
            if (n < 128) {
                int i = (n & 63) >> 1;
                int t = (int)(mrow & 4095);
                float inv = __builtin_exp2f((float)i * (-13.287712379549449f / 32.f));
                float ang = (float)t * inv;
                float sn, cs;
                __sincosf(ang, &sn, &cs);
                float res = (n & 1) ? (partner * sn + val * cs)
                                    : (val * cs - partner * sn);
                if (n < 64) {
                    res *= 0.180336884f;    // (1/8)*log2(e) folded into q
                    qb[mrow * 64 + n] = (__bf16)res;
                } else {
                    kb[mrow * 64 + (n - 64)] = (__bf16)res;
                }
            } else {
                int bb = (int)(mrow >> 12), tt = (int)(mrow & 4095);
                vt[((size_t)bb * 64 + (n - 128)) * 4096 + tt] = (__bf16)val;
            }
        }
    }
}

// ---------------- causal flash attention, 32x32 MFMA, pi-permuted kv ----------
// 256 blocks = 4 batches x 64 pairs; each block serially does jt=127-p (heavy)
// then jt=p (light) -> every CU runs a balanced heavy+light mix (round-5 proven).
// 8 waves = 8 k-splits of 64-row k-tiles; wave owns all 32 q-rows.
// Swapped QK^T (lane -> one q col); K rows pi-permuted so P->B-frag repack is a
// pure register rename. K and V register double-buffered ACROSS iterations:
// next tile's K issued right after QK consumes kfA, next V right after PV.
__global__ __launch_bounds__(512, 2) void flash_kernel(
    const __bf16* __restrict__ qb, const __bf16* __restrict__ kb,
    const __bf16* __restrict__ vt, float* __restrict__ out)
{
    __shared__ float ods[8][32][68];
    __shared__ float mls[2][8][32];

    const int tid = threadIdx.x;
    const int wave = tid >> 6, lane = tid & 63;
    const int l31 = lane & 31, h = lane >> 5;
    const int b = blockIdx.x & 3;
    const int p = blockIdx.x >> 2;
    // pi bit-shuffle: [b4 b3 b2 b1 b0] -> row with b3->16s, b2->8s, b4->4s
    const int prow = ((l31 >> 3) & 1) * 16 + ((l31 >> 2) & 1) * 8
                   + (l31 >> 4) * 4 + (l31 & 3);

    const __bf16* kbb = kb + (size_t)b * T_LEN * 64;
    const __bf16* vtb = vt + (size_t)b * 64 * T_LEN;

    #pragma unroll 1
    for (int half = 0; half < 2; half++) {
        const int jt = half ? p : 127 - p;
        const int q0 = jt * 32;
        const int qg = q0 + l31;

        // Q B-frags: col q = l31, k(d) = dc*16 + 8h + j  (q pre-scaled in proj)
        const __bf16* qp = qb + ((size_t)b * T_LEN + q0 + l31) * 64 + h * 8;
        bf16x8 qf[4];
        #pragma unroll
        for (int dc = 0; dc < 4; dc++) qf[dc] = *(const bf16x8*)(qp + dc * 16);

        float m = 16.f, l = 0.f;
        f32x16 o0 = zero16(), o1 = zero16();
        const int nt = (jt >> 1) + 1;   // 64-row k-tiles

        int kt = wave;
        bf16x8 kfA[8], vfA0[4], vfA1[4];
        if (kt < nt) {   // prologue: first tile's K+V into regs
            const __bf16* kr = kbb + (size_t)((kt << 6) + prow) * 64 + h * 8;
            #pragma unroll
            for (int dc = 0; dc < 4; dc++) {
                kfA[dc]     = *(const bf16x8*)(kr + dc * 16);
                kfA[4 + dc] = *(const bf16x8*)(kr + 2048 + dc * 16);
            }
            const __bf16* vr0 = vtb + (size_t)l31 * T_LEN + (kt << 6) + h * 8;
            const __bf16* vr1 = vr0 + (size_t)32 * T_LEN;
            #pragma unroll
            for (int cg = 0; cg < 4; cg++) {
                vfA0[cg] = *(const bf16x8*)(vr0 + cg * 16);
                vfA1[cg] = *(const bf16x8*)(vr1 + cg * 16);
            }
        }

        #pragma unroll 1
        for (; kt < nt; kt += 8) {
            const int kc0 = kt << 6;
            const int ktn = (kt + 8 < nt) ? kt + 8 : kt;   // clamped prefetch idx
            // QK^T (consumes kfA)
            f32x16 s0 = zero16(), s1 = zero16();
            __builtin_amdgcn_s_setprio(1);
            #pragma unroll
            for (int dc = 0; dc < 4; dc++) {
                s0 = mfma32(kfA[dc], qf[dc], s0);
                s1 = mfma32(kfA[4 + dc], qf[dc], s1);
            }
            __builtin_amdgcn_s_setprio(0);
            // issue NEXT tile's K loads now: in flight across softmax+PV+backedge
            {
                const __bf16* krn = kbb + (size_t)((ktn << 6) + prow) * 64 + h * 8;
                #pragma unroll
                for (int dc = 0; dc < 4; dc++) {
                    kfA[dc]     = *(const bf16x8*)(krn + dc * 16);
                    kfA[4 + dc] = *(const bf16x8*)(krn + 2048 + dc * 16);
                }
            }
            // causal mask: only diagonal-straddling tiles (wave-uniform guard)
            if (kc0 + 63 > q0) {
                #pragma unroll
                for (int r = 0; r < 16; r++) {
                    int koff = kc0 + ((r >> 2) & 1) * 16 + 8 * h
                             + (r >> 3) * 4 + (r & 3);
                    if (koff > qg)      s0[r] = -1e30f;
                    if (koff + 32 > qg) s1[r] = -1e30f;
                }
            }
            // local max tree (defer check only; does NOT gate the exp)
            float tm[8];
            #pragma unroll
            for (int i = 0; i < 8; i++)
                tm[i] = fmaxf(fmaxf(s0[2 * i], s0[2 * i + 1]),
                              fmaxf(s1[2 * i], s1[2 * i + 1]));
            #pragma unroll
            for (int i = 0; i < 4; i++) tm[i] = fmaxf(tm[i], tm[i + 4]);
            float tmax = fmaxf(fmaxf(tm[0], tm[1]), fmaxf(tm[2], tm[3]));
            // exp2 against running base m — no reduction wait on critical path
            float ts[4] = {0.f, 0.f, 0.f, 0.f};
            #pragma unroll
            for (int r = 0; r < 16; r++) {
                float e0 = __builtin_exp2f(s0[r] - m);
                float e1 = __builtin_exp2f(s1[r] - m);
                s0[r] = e0; s1[r] = e1;
                ts[r & 3] += e0 + e1;
            }
            float lsum = (ts[0] + ts[1]) + (ts[2] + ts[3]);
            // cross-half exchanges issued now, consumed after PV
            float lsum_p = __shfl_xor(lsum, 32);
            float tmax_p = __shfl_xor(tmax, 32);
            // P -> B-frags: pure register rename under pi (no shuffles)
            union { u32 w[4]; bf16x8 v; } pf[4];
            #pragma unroll
            for (int cg = 0; cg < 2; cg++) {
                pf[cg].w[0]     = packbf(s0[4 * cg + 0],  s0[4 * cg + 1]);
                pf[cg].w[1]     = packbf(s0[4 * cg + 2],  s0[4 * cg + 3]);
                pf[cg].w[2]     = packbf(s0[4 * cg + 8],  s0[4 * cg + 9]);
                pf[cg].w[3]     = packbf(s0[4 * cg + 10], s0[4 * cg + 11]);
                pf[cg + 2].w[0] = packbf(s1[4 * cg + 0],  s1[4 * cg + 1]);
                pf[cg + 2].w[1] = packbf(s1[4 * cg + 2],  s1[4 * cg + 3]);
                pf[cg + 2].w[2] = packbf(s1[4 * cg + 8],  s1[4 * cg + 9]);
                pf[cg + 2].w[3] = packbf(s1[4 * cg + 10], s1[4 * cg + 11]);
            }
            // PV: O^T += V^T P^T (consumes vfA)
            __builtin_amdgcn_s_setprio(1);
            #pragma unroll
            for (int cg = 0; cg < 4; cg++) {
                o0 = mfma32(vfA0[cg], pf[cg].v, o0);
                o1 = mfma32(vfA1[cg], pf[cg].v, o1);
            }
            __builtin_amdgcn_s_setprio(0);
            // issue NEXT tile's V loads: in flight across backedge + next QK
            {
                const __bf16* vrn0 = vtb + (size_t)l31 * T_LEN + (ktn << 6) + h * 8;
                const __bf16* vrn1 = vrn0 + (size_t)32 * T_LEN;
                #pragma unroll
                for (int cg = 0; cg < 4; cg++) {
                    vfA0[cg] = *(const bf16x8*)(vrn0 + cg * 16);
                    vfA1[cg] = *(const bf16x8*)(vrn1 + cg * 16);
                }
            }
            // fold reductions; rescale AFTER accumulation (tile used base m)
            l += lsum + lsum_p;
            float tmx = fmaxf(tmax, tmax_p);
            if (!__all(tmx <= m + 8.f)) {
                const float mnew = fmaxf(m, tmx);
                const float alpha = __builtin_exp2f(m - mnew);
                m = mnew;
                l *= alpha;
                #pragma unroll
                for (int r = 0; r < 16; r++) { o0[r] *= alpha; o1[r] *= alpha; }
            }
        }

        // publish partials: O^T C-layout col q=l31, row d=(r&3)+8*(r>>2)+4h
        #pragma unroll
        for (int c2 = 0; c2 < 4; c2++) {
            f32x4 w0 = {o0[4 * c2], o0[4 * c2 + 1], o0[4 * c2 + 2], o0[4 * c2 + 3]};
            f32x4 w1 = {o1[4 * c2], o1[4 * c2 + 1], o1[4 * c2 + 2], o1[4 * c2 + 3]};
            *(f32x4*)&ods[wave][l31][8 * c2 + 4 * h]      = w0;
            *(f32x4*)&ods[wave][l31][32 + 8 * c2 + 4 * h] = w1;
        }
        if (h == 0) {
            mls[0][wave][l31] = (wave < nt) ? m : -1e30f;   // empty splits: weight 0
            mls[1][wave][l31] = l;
        }
        __syncthreads();

        // merge 8 splits: thread -> (q = tid>>4, dchunk = tid&15)
        {
            const int q = tid >> 4, dc = tid & 15;
            float M = -1e30f;
            #pragma unroll
            for (int s2 = 0; s2 < 8; s2++) M = fmaxf(M, mls[0][s2][q]);
            float w8[8], L = 0.f;
            #pragma unroll
            for (int s2 = 0; s2 < 8; s2++) {
                float ws = __builtin_exp2f(mls[0][s2][q] - M);
                w8[s2] = ws;
                L += ws * mls[1][s2][q];
            }
            const float invL = 1.f / L;
            f32x4 acc = {0.f, 0.f, 0.f, 0.f};
            #pragma unroll
            for (int s2 = 0; s2 < 8; s2++) {
                f32x4 part = *(const f32x4*)&ods[s2][q][dc * 4];
                acc.x += part.x * w8[s2];
                acc.y += part.y * w8[s2];
                acc.z += part.z * w8[s2];
                acc.w += part.w * w8[s2];
            }
            acc.x *= invL; acc.y *= invL; acc.z *= invL; acc.w *= invL;
            *(f32x4*)(out + ((size_t)b * T_LEN + q0 + q) * 64 + dc * 4) = acc;
        }
        __syncthreads();
    }
}

extern "C" void kernel_launch(void* const* d_in, const int* in_sizes, int n_in,
                              void* d_out, int out_size, void* d_ws, size_t ws_size,
                              hipStream_t stream)
{
    const float* x  = (const float*)d_in[0];
    const float* Wq = (const float*)d_in[1];
    const float* Wk = (const float*)d_in[2];
    const float* Wv = (const float*)d_in[3];
    float* out = (float*)d_out;

    __bf16* qb = (__bf16*)d_ws;          // 2 MB (rope applied, pre-scaled)
    __bf16* kb = qb + 1048576;           // 2 MB (rope applied)
    __bf16* vt = kb + 1048576;           // 2 MB (V transposed [b][d][t])
    __bf16* wb = vt + 1048576;           // 384 KB

    convert_w_kernel<<<192, 256, 0, stream>>>(Wq, Wk, Wv, wb);
    proj_kernel<<<1024, 256, 0, stream>>>(x, wb, qb, kb, vt);
    flash_kernel<<<256, 512, 0, stream>>>(qb, kb, vt, out);
}

// Round 10
// 70.954 us; speedup vs baseline: 1.4047x; 1.4047x over previous
//
#include <hip/hip_runtime.h>

typedef __bf16 bf16x8 __attribute__((ext_vector_type(8)));
typedef __bf16 bf16x4 __attribute__((ext_vector_type(4)));
typedef float f32x4 __attribute__((ext_vector_type(4)));
typedef float f32x16 __attribute__((ext_vector_type(16)));
typedef unsigned int u32;

#define T_LEN 4096

__device__ __forceinline__ f32x4 mfma16(bf16x8 a, bf16x8 b, f32x4 c) {
    return __builtin_amdgcn_mfma_f32_16x16x32_bf16(a, b, c, 0, 0, 0);
}
__device__ __forceinline__ f32x16 mfma32(bf16x8 a, bf16x8 b, f32x16 c) {
    return __builtin_amdgcn_mfma_f32_32x32x16_bf16(a, b, c, 0, 0, 0);
}
__device__ __forceinline__ u32 packbf(float lo, float hi) {
    union { __bf16 e[2]; u32 w; } u;
    u.e[0] = (__bf16)lo; u.e[1] = (__bf16)hi;
    return u.w;
}
__device__ __forceinline__ f32x16 zero16() {
    f32x16 z;
    #pragma unroll
    for (int i = 0; i < 16; i++) z[i] = 0.f;
    return z;
}

// ---------------- W fp32 -> bf16 (ws), vectorized ----------------
__global__ __launch_bounds__(256) void convert_w_kernel(
    const float* __restrict__ Wq, const float* __restrict__ Wk,
    const float* __restrict__ Wv, __bf16* __restrict__ wb)
{
    int i = blockIdx.x * 256 + threadIdx.x;      // 49152 threads, 4 elems each
    int m = i >> 14, off = (i & 16383) << 2;
    const float* s = (m == 0 ? Wq : (m == 1 ? Wk : Wv)) + off;
    float4 f = *(const float4*)s;
    bf16x4 h = { (__bf16)f.x, (__bf16)f.y, (__bf16)f.z, (__bf16)f.w };
    *(bf16x4*)(wb + (m << 16) + off) = h;
}

// ------ QKV projection (M=16384,N=192,K=1024) + fused RoPE + q-prescale ------
// 512 blocks x 32 rows, 8 waves (2M x 4N), reg-staged double-buffer (round-7).
__global__ __launch_bounds__(512, 2) void proj_kernel(
    const float* __restrict__ x, const __bf16* __restrict__ wb,
    __bf16* __restrict__ qb, __bf16* __restrict__ kb, __bf16* __restrict__ vt)
{
    __shared__ __bf16 xs[2][32][72];
    __shared__ __bf16 wl[2][192][72];
    const int tid  = threadIdx.x;
    const int wave = tid >> 6, lane = tid & 63;
    const int l15 = lane & 15, l4 = lane >> 4;
    const int wm = wave >> 2, wn = wave & 3;     // 2 M-halves x 4 N-groups
    const size_t m0 = (size_t)blockIdx.x * 32;
    const int xrow = tid >> 4, xc4 = (tid & 15) * 4;   // x stage: 16 thr/row
    const int wrow = tid >> 3, wcp = (tid & 7) * 8;    // W stage: +64 rows per j

    f32x4 acc[3];
    #pragma unroll
    for (int bn = 0; bn < 3; bn++) acc[bn] = (f32x4){0.f, 0.f, 0.f, 0.f};

    const float* xsrc = x + (m0 + xrow) * 1024 + xc4;

    float4 rx;
    bf16x8 rw[3];

    // prologue: tile 0 -> regs -> LDS buf 0
    rx = *(const float4*)(xsrc);
    #pragma unroll
    for (int j = 0; j < 3; j++)
        rw[j] = *(const bf16x8*)(wb + (size_t)(wrow + j * 64) * 1024 + wcp);
    {
        bf16x4 hx = {(__bf16)rx.x, (__bf16)rx.y, (__bf16)rx.z, (__bf16)rx.w};
        *(bf16x4*)&xs[0][xrow][xc4] = hx;
        #pragma unroll
        for (int j = 0; j < 3; j++)
            *(bf16x8*)&wl[0][wrow + j * 64][wcp] = rw[j];
    }
    __syncthreads();

    for (int t = 0; t < 16; t++) {
        const int cur = t & 1;
        if (t < 15) {   // issue next tile's loads early (overlap with compute)
            const int k0 = (t + 1) * 64;
            rx = *(const float4*)(xsrc + k0);
            #pragma unroll
            for (int j = 0; j < 3; j++)
                rw[j] = *(const bf16x8*)(wb + (size_t)(wrow + j * 64) * 1024 + k0 + wcp);
        }
        // compute tile t from LDS[cur]
        bf16x8 af[2], bfr[3][2];
        #pragma unroll
        for (int c = 0; c < 2; c++)
            af[c] = *(const bf16x8*)&xs[cur][wm * 16 + l15][c * 32 + l4 * 8];
        #pragma unroll
        for (int nf = 0; nf < 3; nf++)
            #pragma unroll
            for (int c = 0; c < 2; c++)
                bfr[nf][c] = *(const bf16x8*)&wl[cur][wn * 48 + nf * 16 + l15][c * 32 + l4 * 8];
        #pragma unroll
        for (int nf = 0; nf < 3; nf++)
            #pragma unroll
            for (int c = 0; c < 2; c++)
                acc[nf] = mfma16(af[c], bfr[nf][c], acc[nf]);
        if (t < 15) {   // stage tile t+1 into the other buffer
            bf16x4 hx = {(__bf16)rx.x, (__bf16)rx.y, (__bf16)rx.z, (__bf16)rx.w};
            *(bf16x4*)&xs[cur ^ 1][xrow][xc4] = hx;
            #pragma unroll
            for (int j = 0; j < 3; j++)
                *(bf16x8*)&wl[cur ^ 1][wrow + j * 64][wcp] = rw[j];
        }
        __syncthreads();
    }

    // epilogue: C layout col = l15 (n), row = l4*4 + r (m); rope fused for q,k;
    // q additionally pre-scaled by (1/8)*log2(e) so flash softmax is base-2 direct.
    #pragma unroll
    for (int nf = 0; nf < 3; nf++) {
        int n = wn * 48 + nf * 16 + l15;
        #pragma unroll
        for (int r = 0; r < 4; r++) {
            size_t mrow = m0 + wm * 16 + l4 * 4 + r;
            float val = acc[nf][r];
            float partner = __shfl_xor(val, 1);
            if (n < 128) {
                int i = (n & 63) >> 1;
                int t = (int)(mrow & 4095);
                float inv = __builtin_exp2f((float)i * (-13.287712379549449f / 32.f));
                float ang = (float)t * inv;
                float sn, cs;
                __sincosf(ang, &sn, &cs);
                float res = (n & 1) ? (partner * sn + val * cs)
                                    : (val * cs - partner * sn);
                if (n < 64) {
                    res *= 0.180336884f;    // (1/8)*log2(e) folded into q
                    qb[mrow * 64 + n] = (__bf16)res;
                } else {
                    kb[mrow * 64 + (n - 64)] = (__bf16)res;
                }
            } else {
                int bb = (int)(mrow >> 12), tt = (int)(mrow & 4095);
                vt[((size_t)bb * 64 + (n - 128)) * 4096 + tt] = (__bf16)val;
            }
        }
    }
}

// ---------------- causal flash attention, 1024-thread blocks ----------------
// 256 blocks = 1/CU guaranteed. XCD-affine: b=(blk&7)>>1 (batch KV ~1MB/XCD L2).
// Each block serially does jt = 127-p (heavy) then jt = p (light) -> balanced.
// 16 waves = 16-way split-K over 32-row k-tiles -> 4 waves/SIMD resident.
// Swapped QK^T (lane -> one q col); K rows pi-permuted so P->B-frag repack is a
// pure register rename. exp2 uses running base m (defer-rescale after PV).
__global__ __launch_bounds__(1024) void flash_kernel(
    const __bf16* __restrict__ qb, const __bf16* __restrict__ kb,
    const __bf16* __restrict__ vt, float* __restrict__ out)
{
    __shared__ float ods[16][32][36];   // two-pass merge buffer (o0 then o1)
    __shared__ float mls[2][16][32];

    const int tid = threadIdx.x;
    const int wave = tid >> 6, lane = tid & 63;
    const int l31 = lane & 31, h = lane >> 5;
    const int xcd = blockIdx.x & 7;
    const int b = xcd >> 1;
    const int p = ((blockIdx.x >> 3) << 1) | (xcd & 1);   // 0..63 per batch
    // pi bit-shuffle: [b4 b3 b2 b1 b0] -> row with b3->16s, b2->8s, b4->4s
    const int prow = ((l31 >> 3) & 1) * 16 + ((l31 >> 2) & 1) * 8
                   + (l31 >> 4) * 4 + (l31 & 3);

    const __bf16* kbb = kb + (size_t)b * T_LEN * 64;
    const __bf16* vtb = vt + (size_t)b * 64 * T_LEN;

    #pragma unroll 1
    for (int half = 0; half < 2; half++) {
        const int jt = half ? p : 127 - p;
        const int q0 = jt * 32;
        const int qg = q0 + l31;

        // Q B-frags: col q = l31, k(d) = dc*16 + 8h + j  (q pre-scaled in proj)
        const __bf16* qp = qb + ((size_t)b * T_LEN + q0 + l31) * 64 + h * 8;
        bf16x8 qf[4];
        #pragma unroll
        for (int dc = 0; dc < 4; dc++) qf[dc] = *(const bf16x8*)(qp + dc * 16);

        float m = 16.f, l = 0.f;
        f32x16 o0 = zero16(), o1 = zero16();
        const int nt = jt + 1;   // 32-row k-tiles

        #pragma unroll 1
        for (int kt = wave; kt < nt; kt += 16) {
            const int kc0 = kt << 5;
            // K A-frags, rows permuted by pi; QK^T
            const __bf16* kr = kbb + (size_t)(kc0 + prow) * 64 + h * 8;
            bf16x8 kf0 = *(const bf16x8*)(kr);
            bf16x8 kf1 = *(const bf16x8*)(kr + 16);
            bf16x8 kf2 = *(const bf16x8*)(kr + 32);
            bf16x8 kf3 = *(const bf16x8*)(kr + 48);
            // V A-frags: rows d = l31(+32), k-slot = cg*16 + 8h + j
            const __bf16* vr0 = vtb + (size_t)l31 * T_LEN + kc0 + h * 8;
            const __bf16* vr1 = vr0 + (size_t)32 * T_LEN;
            bf16x8 vf00 = *(const bf16x8*)(vr0);
            bf16x8 vf01 = *(const bf16x8*)(vr0 + 16);
            bf16x8 vf10 = *(const bf16x8*)(vr1);
            bf16x8 vf11 = *(const bf16x8*)(vr1 + 16);
            f32x16 s = zero16();
            __builtin_amdgcn_s_setprio(1);
            s = mfma32(kf0, qf[0], s);
            s = mfma32(kf1, qf[1], s);
            s = mfma32(kf2, qf[2], s);
            s = mfma32(kf3, qf[3], s);
            __builtin_amdgcn_s_setprio(0);
            // causal mask: only the diagonal tile straddles
            if (kt == jt) {
                #pragma unroll
                for (int r = 0; r < 16; r++) {
                    int pioff = ((r >> 2) & 1) * 16 + 8 * h + (r >> 3) * 4 + (r & 3);
                    if (kc0 + pioff > qg) s[r] = -1e30f;
                }
            }
            // local max tree (defer check only; does NOT gate the exp)
            float tm[8];
            #pragma unroll
            for (int i = 0; i < 8; i++) tm[i] = fmaxf(s[2 * i], s[2 * i + 1]);
            #pragma unroll
            for (int i = 0; i < 4; i++) tm[i] = fmaxf(tm[i], tm[i + 4]);
            float tmax = fmaxf(fmaxf(tm[0], tm[1]), fmaxf(tm[2], tm[3]));
            // exp2 against running base m — no reduction wait on critical path
            float ts[4] = {0.f, 0.f, 0.f, 0.f};
            #pragma unroll
            for (int r = 0; r < 16; r++) {
                float e = __builtin_exp2f(s[r] - m);
                s[r] = e;
                ts[r & 3] += e;
            }
            float lsum = (ts[0] + ts[1]) + (ts[2] + ts[3]);
            // cross-half exchanges issued now, consumed after PV
            float lsum_p = __shfl_xor(lsum, 32);
            float tmax_p = __shfl_xor(tmax, 32);
            // P -> B-frags: pure register rename under pi (no shuffles)
            union { u32 w[4]; bf16x8 v; } pf[2];
            #pragma unroll
            for (int cg = 0; cg < 2; cg++) {
                pf[cg].w[0] = packbf(s[4 * cg + 0],  s[4 * cg + 1]);
                pf[cg].w[1] = packbf(s[4 * cg + 2],  s[4 * cg + 3]);
                pf[cg].w[2] = packbf(s[4 * cg + 8],  s[4 * cg + 9]);
                pf[cg].w[3] = packbf(s[4 * cg + 10], s[4 * cg + 11]);
            }
            // PV: O^T += V^T P^T
            __builtin_amdgcn_s_setprio(1);
            o0 = mfma32(vf00, pf[0].v, o0);
            o0 = mfma32(vf01, pf[1].v, o0);
            o1 = mfma32(vf10, pf[0].v, o1);
            o1 = mfma32(vf11, pf[1].v, o1);
            __builtin_amdgcn_s_setprio(0);
            // fold reductions; rescale AFTER accumulation (tile used base m)
            l += lsum + lsum_p;
            float tmx = fmaxf(tmax, tmax_p);
            if (!__all(tmx <= m + 8.f)) {
                const float mnew = fmaxf(m, tmx);
                const float alpha = __builtin_exp2f(m - mnew);
                m = mnew;
                l *= alpha;
                #pragma unroll
                for (int r = 0; r < 16; r++) { o0[r] *= alpha; o1[r] *= alpha; }
            }
        }

        // ---- two-pass 16-way merge; O^T C-layout col q=l31, row d=(r&3)+8*(r>>2)+4h
        const int q = tid >> 5, dcm = tid & 31;
        // pass A: d = 0..31 (o0)
        #pragma unroll
        for (int c2 = 0; c2 < 4; c2++) {
            f32x4 w0 = {o0[4 * c2], o0[4 * c2 + 1], o0[4 * c2 + 2], o0[4 * c2 + 3]};
            *(f32x4*)&ods[wave][l31][8 * c2 + 4 * h] = w0;
        }
        if (h == 0) {
            mls[0][wave][l31] = (wave < nt) ? m : -1e30f;   // empty splits: weight 0
            mls[1][wave][l31] = l;
        }
        __syncthreads();
        float M = -1e30f;
        #pragma unroll
        for (int s2 = 0; s2 < 16; s2++) M = fmaxf(M, mls[0][s2][q]);
        float w16[16], L = 0.f;
        #pragma unroll
        for (int s2 = 0; s2 < 16; s2++) {
            float ws = __builtin_exp2f(mls[0][s2][q] - M);
            w16[s2] = ws;
            L += ws * mls[1][s2][q];
        }
        const float invL = 1.f / L;
        float accA = 0.f;
        #pragma unroll
        for (int s2 = 0; s2 < 16; s2++) accA += w16[s2] * ods[s2][q][dcm];
        out[((size_t)b * T_LEN + q0 + q) * 64 + dcm] = accA * invL;
        __syncthreads();
        // pass B: d = 32..63 (o1)
        #pragma unroll
        for (int c2 = 0; c2 < 4; c2++) {
            f32x4 w1 = {o1[4 * c2], o1[4 * c2 + 1], o1[4 * c2 + 2], o1[4 * c2 + 3]};
            *(f32x4*)&ods[wave][l31][8 * c2 + 4 * h] = w1;
        }
        __syncthreads();
        float accB = 0.f;
        #pragma unroll
        for (int s2 = 0; s2 < 16; s2++) accB += w16[s2] * ods[s2][q][dcm];
        out[((size_t)b * T_LEN + q0 + q) * 64 + 32 + dcm] = accB * invL;
        __syncthreads();
    }
}

extern "C" void kernel_launch(void* const* d_in, const int* in_sizes, int n_in,
                              void* d_out, int out_size, void* d_ws, size_t ws_size,
                              hipStream_t stream)
{
    const float* x  = (const float*)d_in[0];
    const float* Wq = (const float*)d_in[1];
    const float* Wk = (const float*)d_in[2];
    const float* Wv = (const float*)d_in[3];
    float* out = (float*)d_out;

    __bf16* qb = (__bf16*)d_ws;          // 2 MB (rope applied, pre-scaled)
    __bf16* kb = qb + 1048576;           // 2 MB (rope applied)
    __bf16* vt = kb + 1048576;           // 2 MB (V transposed [b][d][t])
    __bf16* wb = vt + 1048576;           // 384 KB

    convert_w_kernel<<<192, 256, 0, stream>>>(Wq, Wk, Wv, wb);
    proj_kernel<<<512, 512, 0, stream>>>(x, wb, qb, kb, vt);
    flash_kernel<<<256, 1024, 0, stream>>>(qb, kb, vt, out);
}